// Round 1
// 129.007 us; speedup vs baseline: 1.2489x; 1.2489x over previous
//
#include <hip/hip_runtime.h>
#include <math.h>

// KAN layer forward, MI355X.
// NUM_IN = NUM_OUT = 128, SIZE = 16384, BATCH = 512, K = 3 (cubic), G = 5.
//
// Reference semantics:
//   s = o*128 + i ;  pre_acts[s,b]   = x[b,i]
//   post_splines[s,b] = mask[s] * sum_j coef[s,j] * B3_j(x[b,i]; grid_s)
//   post_acts[s,b]    = scale_b[s]*silu(x[b,i]) + scale_spline[s]*post_splines[s,b]
//   y[b,i] = sum_o post_acts[o*128+i, b]
// Outputs concatenated: y (512*128), pre_acts.T, post_splines.T, post_acts.T
// (each 512*16384, layout [b][s]).
//
// This is a write-streaming kernel (~100 MB stores, ~2.5 MB mandatory reads).
// v2 changes vs the 161 us baseline (which ran 512 blocks -> 20% occupancy,
// latency-bound at 1.5 TB/s):
//   - CO 16 -> 4, grid 512 -> 2048 blocks (8 blocks/CU -> full wave-slot
//     occupancy possible at ~<=64 VGPR).
//   - all CO param rows prefetched up front as independent loads (coef via
//     2x float4) -> one overlapped latency window instead of 16 serial
//     dependent-load stalls per thread.
//   - nontemporal stores for the three 32 MB output streams (never re-read;
//     avoids L2 write-allocate thrash: 100 MB >> 32 MB L2).

#define N_IN   128
#define SIZEK  16384
#define BATCH  512

#define TB 4    // batches per thread
#define CO 4    // o-values per thread

__global__ __launch_bounds__(256) void kan_fwd(
    const float* __restrict__ x,            // [512][128]
    const float* __restrict__ scale_b,      // [16384]
    const float* __restrict__ scale_spline, // [16384]
    const float* __restrict__ coef,         // [16384][8]
    const float* __restrict__ mask,         // [16384]
    const float* __restrict__ knots,        // [16384][6]
    float* __restrict__ y,                  // [512][128] (pre-zeroed)
    float* __restrict__ pre_out,            // [512][16384]
    float* __restrict__ spl_out,            // [512][16384]
    float* __restrict__ post_out)           // [512][16384]
{
    const int g  = blockIdx.x * blockDim.x + threadIdx.x;
    const int i  = g & 127;          // input index (lane-consecutive -> coalesced)
    const int r  = g >> 7;
    const int oc = r & 31;           // o-chunk id (32 chunks of 4)
    const int bg = r >> 5;           // batch-group id (128 groups of 4)
    const int o0 = oc << 2;
    const int b0 = bg << 2;

    float xv[TB], sil[TB], ysum[TB];
#pragma unroll
    for (int t = 0; t < TB; ++t) {
        const float xx = x[(b0 + t) * N_IN + i];
        xv[t]   = xx;
        sil[t]  = xx / (1.0f + __expf(-xx));   // silu(x) = x * sigmoid(x)
        ysum[t] = 0.0f;
    }

    // ---- prefetch all CO param rows (independent loads -> one waitcnt batch)
    float e0v[CO], ihv[CO], mkv[CO], sbv[CO], ssv[CO];
    float4 cA[CO], cB[CO];
#pragma unroll
    for (int oo = 0; oo < CO; ++oo) {
        const int s = ((o0 + oo) << 7) | i;
        const float k0 = knots[s * 6];
        const float k5 = knots[s * 6 + 5];
        const float h  = (k5 - k0) * 0.2f;     // (g_last-g_first)/G, G=5
        ihv[oo] = 1.0f / h;
        e0v[oo] = k0 - 3.0f * h;               // leftmost extended knot
        mkv[oo] = mask[s];
        sbv[oo] = scale_b[s];
        ssv[oo] = scale_spline[s];
        const float4* c4 = (const float4*)(coef + (size_t)s * 8);
        cA[oo] = c4[0];
        cB[oo] = c4[1];
    }

#pragma unroll
    for (int oo = 0; oo < CO; ++oo) {
        const int s = ((o0 + oo) << 7) | i;
        const float e0   = e0v[oo];
        const float invh = ihv[oo];
        const float mk   = mkv[oo];
        const float sb   = sbv[oo];
        const float ss   = ssv[oo];
        const float cf[8] = { cA[oo].x, cA[oo].y, cA[oo].z, cA[oo].w,
                              cB[oo].x, cB[oo].y, cB[oo].z, cB[oo].w };

#pragma unroll
        for (int t = 0; t < TB; ++t) {
            const float u  = (xv[t] - e0) * invh;
            const float mf = floorf(u);
            const int   m  = (int)mf;
            const float tt = u - mf;               // fractional position in interval
            const bool inr = (m >= 0) && (m <= 10); // inside extended grid?

            const float t2  = tt * tt;
            const float t3  = t2 * tt;
            const float omt = 1.0f - tt;
            float w[4];
            w[0] = omt * omt * omt * (1.0f / 6.0f);
            w[1] = (3.0f * t3 - 6.0f * t2 + 4.0f) * (1.0f / 6.0f);
            w[2] = (-3.0f * t3 + 3.0f * t2 + 3.0f * tt + 1.0f) * (1.0f / 6.0f);
            w[3] = t3 * (1.0f / 6.0f);

            const int jlo = m - 3;
            float spline = 0.0f;
#pragma unroll
            for (int rr = 0; rr < 4; ++rr) {
                const int j  = jlo + rr;
                const int jc = min(max(j, 0), 7);   // clamp: keep access in-bounds
                const float c  = cf[jc];
                const float wv = (inr && j >= 0 && j <= 7) ? w[rr] : 0.0f;
                spline = fmaf(c, wv, spline);
            }

            const float splm = spline * mk;
            const float post = fmaf(sb, sil[t], ss * splm);

            const size_t idx = (size_t)(b0 + t) * SIZEK + (size_t)s;
            __builtin_nontemporal_store(xv[t], &pre_out[idx]);
            __builtin_nontemporal_store(splm, &spl_out[idx]);
            __builtin_nontemporal_store(post, &post_out[idx]);
            ysum[t] += post;
        }
    }

#pragma unroll
    for (int t = 0; t < TB; ++t)
        atomicAdd(&y[(b0 + t) * N_IN + i], ysum[t]);
}

extern "C" void kernel_launch(void* const* d_in, const int* in_sizes, int n_in,
                              void* d_out, int out_size, void* d_ws, size_t ws_size,
                              hipStream_t stream) {
    const float* x            = (const float*)d_in[0];
    const float* scale_b      = (const float*)d_in[1];
    const float* scale_spline = (const float*)d_in[2];
    const float* coef         = (const float*)d_in[3];
    const float* mask         = (const float*)d_in[4];
    const float* knots        = (const float*)d_in[5];

    float* out  = (float*)d_out;
    float* y    = out;                         // 512*128      = 65536
    float* pre  = y + 512 * 128;               // 512*16384    = 8388608
    float* spl  = pre + (size_t)512 * 16384;
    float* post = spl + (size_t)512 * 16384;

    // y is accumulated with atomics; harness poisons d_out with 0xAA.
    hipMemsetAsync(y, 0, 512 * 128 * sizeof(float), stream);

    // threads = 128 i * 32 o-chunks * 128 b-groups = 524288 -> 2048 blocks
    dim3 grid(2048), block(256);
    kan_fwd<<<grid, block, 0, stream>>>(x, scale_b, scale_spline, coef, mask,
                                        knots, y, pre, spl, post);
}